// Round 2
// baseline (409.058 us; speedup 1.0000x reference)
//
#include <hip/hip_runtime.h>

// Attend: out = softmax(causal(Q K^T * 0.125 + bias)) @ V
// B=4,H=16,N=1024,D=64. fp32 I/O, bf16 MFMA compute.
// Block = 64 q-rows of one head; 4 waves x 16 rows; j-tiles of 64.
// Round 2: raw s_barrier + lgkmcnt-only drain (T4). __syncthreads() emits
// s_waitcnt vmcnt(0) which flushed the whole software pipeline twice per
// tile; raw barriers let the compiler's counted vmcnt waits keep K/V/bias
// prefetch loads in flight across barriers. + T5 setprio around MFMA.

#define BHn 64
#define Nn 1024
#define Dn 64
#define NEG_BIG (-1e30f)

typedef __attribute__((ext_vector_type(8))) short short8;
typedef __attribute__((ext_vector_type(4))) float floatx4;
typedef __attribute__((ext_vector_type(2))) unsigned uint2v;
typedef __attribute__((ext_vector_type(4))) unsigned uint4v;

// Workgroup barrier WITHOUT the vmcnt(0) drain __syncthreads() emits.
// Each wave drains its own LDS ops (lgkmcnt) so cross-wave LDS RAW/WAR is
// safe; global-load prefetches stay in flight (compiler inserts counted
// vmcnt at first use). Pattern verified in the 8-phase GEMM template.
#define BARRIER_LDS()                                            \
    do {                                                         \
        asm volatile("s_waitcnt lgkmcnt(0)" ::: "memory");       \
        __builtin_amdgcn_s_barrier();                            \
    } while (0)

__device__ __forceinline__ unsigned cvt_pk_bf16(float lo, float hi) {
    unsigned r;
    asm("v_cvt_pk_bf16_f32 %0, %1, %2" : "=v"(r) : "v"(lo), "v"(hi));
    return r;   // packed {bf16(lo), bf16(hi)}, RNE
}

__global__ __launch_bounds__(256, 4) void attend_mfma(
    const float* __restrict__ q, const float* __restrict__ kk,
    const float* __restrict__ v, const float* __restrict__ bias,
    float* __restrict__ out)
{
    const int bh = blockIdx.x >> 4;
    const int qt = 15 - (blockIdx.x & 15);   // long blocks dispatched first
    const int i0 = qt * 64;
    const int tid  = threadIdx.x;
    const int lane = tid & 63;
    const int wave = tid >> 6;
    const int ln = lane & 15;                // MFMA n / m index
    const int lg = lane >> 4;                // MFMA k-group / row-group

    // stride 80 shorts = 160 B: 16B-aligned rows.
    __shared__ short k_s[64][80];            // K tile, row-major [j][d]
    __shared__ short vt_s[64][80];           // V tile, transposed [d][j]
    __shared__ short p_s[4][16][80];         // per-wave P tile [m][j]

    // ---- preload Q A-frags (2 k-parts of K=32), fp32 -> bf16 ----
    short8 qa[2];
    {
        const float* qp = q + ((long)(bh * Nn + i0 + wave * 16 + ln)) * Dn + lg * 8;
#pragma unroll
        for (int kp = 0; kp < 2; ++kp) {
            floatx4 f0 = *(const floatx4*)(qp + kp * 32);
            floatx4 f1 = *(const floatx4*)(qp + kp * 32 + 4);
            union { short8 s; unsigned u[4]; } qq;
            qq.u[0] = cvt_pk_bf16(f0[0], f0[1]);
            qq.u[1] = cvt_pk_bf16(f0[2], f0[3]);
            qq.u[2] = cvt_pk_bf16(f1[0], f1[1]);
            qq.u[3] = cvt_pk_bf16(f1[2], f1[3]);
            qa[kp] = qq.s;
        }
    }

    short8 ones;
#pragma unroll
    for (int i = 0; i < 8; ++i) ones[i] = (short)0x3F80;   // bf16 1.0

    floatx4 o_acc[4];
#pragma unroll
    for (int dt = 0; dt < 4; ++dt) o_acc[dt] = (floatx4){0.f, 0.f, 0.f, 0.f};
    floatx4 l_acc = {0.f, 0.f, 0.f, 0.f};

    const int irow0 = i0 + wave * 16;
    const long bias_base = ((long)bh) << 20;           // bh * N * N

    // ---- register prefetch buffers (tile jt staged from regs loaded at jt-1) ----
    floatx4 kpf[4];      // 16 floats: K tile slice for this thread
    float   vpf[16];     // 16 floats: V tile slice (strided rows, col=lane)
    float   bv[4][4];    // bias values for this thread's P fragment

    // ---- prologue: prefetch tile 0 ----
    {
        const float* kb = kk + ((long)(bh * Nn)) * Dn;
#pragma unroll
        for (int it = 0; it < 4; ++it)
            kpf[it] = *(const floatx4*)(kb + it * 1024 + tid * 4);
        const float* vb = v + ((long)(bh * Nn)) * Dn;
#pragma unroll
        for (int r = 0; r < 16; ++r)
            vpf[r] = vb[(wave * 16 + r) * Dn + lane];      // coalesced across lanes
#pragma unroll
        for (int nt = 0; nt < 4; ++nt)
#pragma unroll
            for (int r = 0; r < 4; ++r)
                bv[nt][r] = bias[bias_base + (long)(irow0 + lg * 4 + r) * Nn
                                 + nt * 16 + ln];
    }

    for (int jt = 0; jt <= qt; ++jt) {
        const int j0 = jt * 64;

        BARRIER_LDS();                       // prior-tile LDS readers done

        // ---- stage K tile from regs: cvt + ds_write only ----
        // (compiler inserts counted vmcnt here for kpf/vpf arrival)
#pragma unroll
        for (int it = 0; it < 4; ++it) {
            const int e = it * 1024 + tid * 4;
            uint2v w;
            w.x = cvt_pk_bf16(kpf[it][0], kpf[it][1]);
            w.y = cvt_pk_bf16(kpf[it][2], kpf[it][3]);
            *(uint2v*)&k_s[e >> 6][e & 63] = w;
        }
        // ---- stage V tile transposed from regs ----
        {
            uint4v lo, hi;
            lo.x = cvt_pk_bf16(vpf[0],  vpf[1]);
            lo.y = cvt_pk_bf16(vpf[2],  vpf[3]);
            lo.z = cvt_pk_bf16(vpf[4],  vpf[5]);
            lo.w = cvt_pk_bf16(vpf[6],  vpf[7]);
            hi.x = cvt_pk_bf16(vpf[8],  vpf[9]);
            hi.y = cvt_pk_bf16(vpf[10], vpf[11]);
            hi.z = cvt_pk_bf16(vpf[12], vpf[13]);
            hi.w = cvt_pk_bf16(vpf[14], vpf[15]);
            *(uint4v*)&vt_s[lane][wave * 16]     = lo;
            *(uint4v*)&vt_s[lane][wave * 16 + 8] = hi;
        }

        BARRIER_LDS();                       // tile jt visible to all waves

        // ---- issue K/V prefetch for tile jt+1 (stays in flight past barriers) ----
        if (jt < qt) {
            const float* kbn = kk + ((long)(bh * Nn + j0 + 64)) * Dn;
#pragma unroll
            for (int it = 0; it < 4; ++it)
                kpf[it] = *(const floatx4*)(kbn + it * 1024 + tid * 4);
            const float* vbn = v + ((long)(bh * Nn + j0 + 64)) * Dn;
#pragma unroll
            for (int r = 0; r < 16; ++r)
                vpf[r] = vbn[(wave * 16 + r) * Dn + lane];
        }

        // ---- S = Q K^T (8 mfma) ----
        floatx4 sfr[4];
        __builtin_amdgcn_s_setprio(1);
#pragma unroll
        for (int nt = 0; nt < 4; ++nt) {
            short8 b0 = *(const short8*)&k_s[nt * 16 + ln][lg * 8];
            short8 b1 = *(const short8*)&k_s[nt * 16 + ln][32 + lg * 8];
            floatx4 acc = {0.f, 0.f, 0.f, 0.f};
            acc = __builtin_amdgcn_mfma_f32_16x16x32_bf16(qa[0], b0, acc, 0, 0, 0);
            acc = __builtin_amdgcn_mfma_f32_16x16x32_bf16(qa[1], b1, acc, 0, 0, 0);
            sfr[nt] = acc;
        }
        __builtin_amdgcn_s_setprio(0);

        // ---- P = exp(scale*S + bias), causal-masked on diagonal tile ----
        // (compiler inserts counted vmcnt here for bv arrival)
        const bool diag = (jt == qt);
#pragma unroll
        for (int nt = 0; nt < 4; ++nt) {
#pragma unroll
            for (int r = 0; r < 4; ++r) {
                float sv = sfr[nt][r] * 0.125f + bv[nt][r];
                if (diag) {
                    const int i_ = irow0 + lg * 4 + r;
                    const int j_ = j0 + nt * 16 + ln;
                    sv = (j_ > i_) ? NEG_BIG : sv;
                }
                const float p  = __expf(sv);
                const float po = __shfl_xor(p, 1);
                if (!(lane & 1)) {           // even lane packs (ln, ln+1) -> b32
                    *(unsigned*)&p_s[wave][lg * 4 + r][nt * 16 + ln] =
                        cvt_pk_bf16(p, po);
                }
            }
        }

        // ---- issue bias prefetch for tile jt+1 (bv now dead) ----
        if (jt < qt) {
            const int j1 = j0 + 64;
#pragma unroll
            for (int nt = 0; nt < 4; ++nt)
#pragma unroll
                for (int r = 0; r < 4; ++r)
                    bv[nt][r] = bias[bias_base + (long)(irow0 + lg * 4 + r) * Nn
                                     + j1 + nt * 16 + ln];
        }

        // ---- P A-frags (wave-local LDS round trip) ----
        const short8 pa0 = *(const short8*)&p_s[wave][ln][lg * 8];
        const short8 pa1 = *(const short8*)&p_s[wave][ln][32 + lg * 8];

        __builtin_amdgcn_s_setprio(1);
        // ---- l += P . ones (row-sums, same C layout as O) ----
        l_acc = __builtin_amdgcn_mfma_f32_16x16x32_bf16(pa0, ones, l_acc, 0, 0, 0);
        l_acc = __builtin_amdgcn_mfma_f32_16x16x32_bf16(pa1, ones, l_acc, 0, 0, 0);

        // ---- O += P V (8 mfma) ----
#pragma unroll
        for (int dt = 0; dt < 4; ++dt) {
            short8 vb0 = *(const short8*)&vt_s[dt * 16 + ln][lg * 8];
            short8 vb1 = *(const short8*)&vt_s[dt * 16 + ln][32 + lg * 8];
            o_acc[dt] = __builtin_amdgcn_mfma_f32_16x16x32_bf16(pa0, vb0, o_acc[dt], 0, 0, 0);
            o_acc[dt] = __builtin_amdgcn_mfma_f32_16x16x32_bf16(pa1, vb1, o_acc[dt], 0, 0, 0);
        }
        __builtin_amdgcn_s_setprio(0);
    }

    // ---- epilogue: out = O / l, fp32 stores ----
#pragma unroll
    for (int r = 0; r < 4; ++r) {
        const float linv = 1.0f / l_acc[r];
        const long orow = ((long)(bh * Nn + irow0 + lg * 4 + r)) * Dn;
#pragma unroll
        for (int dt = 0; dt < 4; ++dt)
            out[orow + dt * 16 + ln] = o_acc[dt][r] * linv;
    }
}

extern "C" void kernel_launch(void* const* d_in, const int* in_sizes, int n_in,
                              void* d_out, int out_size, void* d_ws, size_t ws_size,
                              hipStream_t stream) {
    const float* q    = (const float*)d_in[0];
    const float* k    = (const float*)d_in[1];
    const float* v    = (const float*)d_in[2];
    const float* bias = (const float*)d_in[3];
    float* out = (float*)d_out;

    dim3 grid(BHn * 16);   // 64 heads x 16 q-tiles of 64 rows
    dim3 block(256);
    attend_mfma<<<grid, block, 0, stream>>>(q, k, v, bias, out);
}

// Round 3
// 392.041 us; speedup vs baseline: 1.0434x; 1.0434x over previous
//
#include <hip/hip_runtime.h>

// Attend: out = softmax(causal(Q K^T * 0.125 + bias)) @ V
// B=4,H=16,N=1024,D=64. fp32 I/O, bf16 MFMA compute.
// Block = 64 q-rows of one head; 4 waves x 16 rows; j-tiles of 64.
// Round 3: per-CU load balancing. All 1024 blocks are co-resident (4/CU,
// round-robin => co-resident set {c,c+256,c+512,c+768}). Old qt=f(b&15)
// gave every CU 4 blocks of IDENTICAL qt -> qt=15 CUs did 64 iters while
// qt=0 CUs idled after 4 (wall ~1.9x balanced). New (h,qt) map balances
// sum(qt+1)=~34 per co-resident set under both round-robin and chunked
// assignment, and pins each head's 16 blocks to one XCD (L2 K/V reuse).
// Also: LDS row stride 80->72 shorts (144B): V-write 16-way conflict ->
// floor, P-write 4-way -> free, QK/PV reads stay at floor.

#define BHn 64
#define Nn 1024
#define Dn 64
#define NEG_BIG (-1e30f)
#define STR 72   // LDS row stride in shorts (144 B = 9*16B)

typedef __attribute__((ext_vector_type(8))) short short8;
typedef __attribute__((ext_vector_type(4))) float floatx4;
typedef __attribute__((ext_vector_type(2))) unsigned uint2v;
typedef __attribute__((ext_vector_type(4))) unsigned uint4v;

// Workgroup barrier WITHOUT the vmcnt(0) drain __syncthreads() emits:
// drain own LDS ops only; global prefetches stay in flight.
#define BARRIER_LDS()                                            \
    do {                                                         \
        asm volatile("s_waitcnt lgkmcnt(0)" ::: "memory");       \
        __builtin_amdgcn_s_barrier();                            \
    } while (0)

__device__ __forceinline__ unsigned cvt_pk_bf16(float lo, float hi) {
    unsigned r;
    asm("v_cvt_pk_bf16_f32 %0, %1, %2" : "=v"(r) : "v"(lo), "v"(hi));
    return r;   // packed {bf16(lo), bf16(hi)}, RNE
}

__global__ __launch_bounds__(256, 4) void attend_mfma(
    const float* __restrict__ q, const float* __restrict__ kk,
    const float* __restrict__ v, const float* __restrict__ bias,
    float* __restrict__ out)
{
    // ---- balanced (head, qtile) decode ----
    const int b  = blockIdx.x;
    const int bh = b & 63;                   // 16 blocks/head, same XCD
    const int t  = b >> 6;
    const int kq_ = t >> 2, t0 = t & 3;
    const int qt = kq_ + 4 * ((t0 + kq_ + bh) & 3);   // bijective per head,
                                                      // qt-balanced per CU
    const int i0 = qt * 64;
    const int tid  = threadIdx.x;
    const int lane = tid & 63;
    const int wave = tid >> 6;
    const int ln = lane & 15;                // MFMA n / m index
    const int lg = lane >> 4;                // MFMA k-group / row-group

    __shared__ short k_s[64][STR];           // K tile, row-major [j][d]
    __shared__ short vt_s[64][STR];          // V tile, transposed [d][j]
    __shared__ short p_s[4][16][STR];        // per-wave P tile [m][j]

    // ---- preload Q A-frags (2 k-parts of K=32), fp32 -> bf16 ----
    short8 qa[2];
    {
        const float* qp = q + ((long)(bh * Nn + i0 + wave * 16 + ln)) * Dn + lg * 8;
#pragma unroll
        for (int kp = 0; kp < 2; ++kp) {
            floatx4 f0 = *(const floatx4*)(qp + kp * 32);
            floatx4 f1 = *(const floatx4*)(qp + kp * 32 + 4);
            union { short8 s; unsigned u[4]; } qq;
            qq.u[0] = cvt_pk_bf16(f0[0], f0[1]);
            qq.u[1] = cvt_pk_bf16(f0[2], f0[3]);
            qq.u[2] = cvt_pk_bf16(f1[0], f1[1]);
            qq.u[3] = cvt_pk_bf16(f1[2], f1[3]);
            qa[kp] = qq.s;
        }
    }

    short8 ones;
#pragma unroll
    for (int i = 0; i < 8; ++i) ones[i] = (short)0x3F80;   // bf16 1.0

    floatx4 o_acc[4];
#pragma unroll
    for (int dt = 0; dt < 4; ++dt) o_acc[dt] = (floatx4){0.f, 0.f, 0.f, 0.f};
    floatx4 l_acc = {0.f, 0.f, 0.f, 0.f};

    const int irow0 = i0 + wave * 16;
    const long bias_base = ((long)bh) << 20;           // bh * N * N

    // ---- register prefetch buffers ----
    floatx4 kpf[4];      // 16 floats: K tile slice
    float   vpf[16];     // 16 floats: V tile slice (strided rows, col=lane)
    float   bv[4][4];    // bias values for this thread's P fragment

    // ---- prologue: prefetch tile 0 ----
    {
        const float* kb = kk + ((long)(bh * Nn)) * Dn;
#pragma unroll
        for (int it = 0; it < 4; ++it)
            kpf[it] = *(const floatx4*)(kb + it * 1024 + tid * 4);
        const float* vb = v + ((long)(bh * Nn)) * Dn;
#pragma unroll
        for (int r = 0; r < 16; ++r)
            vpf[r] = vb[(wave * 16 + r) * Dn + lane];      // coalesced across lanes
#pragma unroll
        for (int nt = 0; nt < 4; ++nt)
#pragma unroll
            for (int r = 0; r < 4; ++r)
                bv[nt][r] = bias[bias_base + (long)(irow0 + lg * 4 + r) * Nn
                                 + nt * 16 + ln];
    }

    for (int jt = 0; jt <= qt; ++jt) {
        const int j0 = jt * 64;

        BARRIER_LDS();                       // prior-tile LDS readers done

        // ---- stage K tile from regs: cvt + ds_write only ----
#pragma unroll
        for (int it = 0; it < 4; ++it) {
            const int e = it * 1024 + tid * 4;
            uint2v w;
            w.x = cvt_pk_bf16(kpf[it][0], kpf[it][1]);
            w.y = cvt_pk_bf16(kpf[it][2], kpf[it][3]);
            *(uint2v*)&k_s[e >> 6][e & 63] = w;
        }
        // ---- stage V tile transposed from regs ----
        {
            uint4v lo, hi;
            lo.x = cvt_pk_bf16(vpf[0],  vpf[1]);
            lo.y = cvt_pk_bf16(vpf[2],  vpf[3]);
            lo.z = cvt_pk_bf16(vpf[4],  vpf[5]);
            lo.w = cvt_pk_bf16(vpf[6],  vpf[7]);
            hi.x = cvt_pk_bf16(vpf[8],  vpf[9]);
            hi.y = cvt_pk_bf16(vpf[10], vpf[11]);
            hi.z = cvt_pk_bf16(vpf[12], vpf[13]);
            hi.w = cvt_pk_bf16(vpf[14], vpf[15]);
            *(uint4v*)&vt_s[lane][wave * 16]     = lo;
            *(uint4v*)&vt_s[lane][wave * 16 + 8] = hi;
        }

        BARRIER_LDS();                       // tile jt visible to all waves

        // ---- issue K/V prefetch for tile jt+1 ----
        if (jt < qt) {
            const float* kbn = kk + ((long)(bh * Nn + j0 + 64)) * Dn;
#pragma unroll
            for (int it = 0; it < 4; ++it)
                kpf[it] = *(const floatx4*)(kbn + it * 1024 + tid * 4);
            const float* vbn = v + ((long)(bh * Nn + j0 + 64)) * Dn;
#pragma unroll
            for (int r = 0; r < 16; ++r)
                vpf[r] = vbn[(wave * 16 + r) * Dn + lane];
        }

        // ---- S = Q K^T (8 mfma) ----
        floatx4 sfr[4];
        __builtin_amdgcn_s_setprio(1);
#pragma unroll
        for (int nt = 0; nt < 4; ++nt) {
            short8 b0 = *(const short8*)&k_s[nt * 16 + ln][lg * 8];
            short8 b1 = *(const short8*)&k_s[nt * 16 + ln][32 + lg * 8];
            floatx4 acc = {0.f, 0.f, 0.f, 0.f};
            acc = __builtin_amdgcn_mfma_f32_16x16x32_bf16(qa[0], b0, acc, 0, 0, 0);
            acc = __builtin_amdgcn_mfma_f32_16x16x32_bf16(qa[1], b1, acc, 0, 0, 0);
            sfr[nt] = acc;
        }
        __builtin_amdgcn_s_setprio(0);

        // ---- P = exp(scale*S + bias), causal-masked on diagonal tile ----
        const bool diag = (jt == qt);
#pragma unroll
        for (int nt = 0; nt < 4; ++nt) {
#pragma unroll
            for (int r = 0; r < 4; ++r) {
                float sv = sfr[nt][r] * 0.125f + bv[nt][r];
                if (diag) {
                    const int i_ = irow0 + lg * 4 + r;
                    const int j_ = j0 + nt * 16 + ln;
                    sv = (j_ > i_) ? NEG_BIG : sv;
                }
                const float p  = __expf(sv);
                const float po = __shfl_xor(p, 1);
                if (!(lane & 1)) {           // even lane packs (ln, ln+1) -> b32
                    *(unsigned*)&p_s[wave][lg * 4 + r][nt * 16 + ln] =
                        cvt_pk_bf16(p, po);
                }
            }
        }

        // ---- issue bias prefetch for tile jt+1 (bv now dead) ----
        if (jt < qt) {
            const int j1 = j0 + 64;
#pragma unroll
            for (int nt = 0; nt < 4; ++nt)
#pragma unroll
                for (int r = 0; r < 4; ++r)
                    bv[nt][r] = bias[bias_base + (long)(irow0 + lg * 4 + r) * Nn
                                     + j1 + nt * 16 + ln];
        }

        // ---- P A-frags (wave-local LDS round trip) ----
        const short8 pa0 = *(const short8*)&p_s[wave][ln][lg * 8];
        const short8 pa1 = *(const short8*)&p_s[wave][ln][32 + lg * 8];

        __builtin_amdgcn_s_setprio(1);
        // ---- l += P . ones (row-sums, same C layout as O) ----
        l_acc = __builtin_amdgcn_mfma_f32_16x16x32_bf16(pa0, ones, l_acc, 0, 0, 0);
        l_acc = __builtin_amdgcn_mfma_f32_16x16x32_bf16(pa1, ones, l_acc, 0, 0, 0);

        // ---- O += P V (8 mfma) ----
#pragma unroll
        for (int dt = 0; dt < 4; ++dt) {
            short8 vb0 = *(const short8*)&vt_s[dt * 16 + ln][lg * 8];
            short8 vb1 = *(const short8*)&vt_s[dt * 16 + ln][32 + lg * 8];
            o_acc[dt] = __builtin_amdgcn_mfma_f32_16x16x32_bf16(pa0, vb0, o_acc[dt], 0, 0, 0);
            o_acc[dt] = __builtin_amdgcn_mfma_f32_16x16x32_bf16(pa1, vb1, o_acc[dt], 0, 0, 0);
        }
        __builtin_amdgcn_s_setprio(0);
    }

    // ---- epilogue: out = O / l, fp32 stores ----
#pragma unroll
    for (int r = 0; r < 4; ++r) {
        const float linv = 1.0f / l_acc[r];
        const long orow = ((long)(bh * Nn + irow0 + lg * 4 + r)) * Dn;
#pragma unroll
        for (int dt = 0; dt < 4; ++dt)
            out[orow + dt * 16 + ln] = o_acc[dt][r] * linv;
    }
}

extern "C" void kernel_launch(void* const* d_in, const int* in_sizes, int n_in,
                              void* d_out, int out_size, void* d_ws, size_t ws_size,
                              hipStream_t stream) {
    const float* q    = (const float*)d_in[0];
    const float* k    = (const float*)d_in[1];
    const float* v    = (const float*)d_in[2];
    const float* bias = (const float*)d_in[3];
    float* out = (float*)d_out;

    dim3 grid(BHn * 16);   // 64 heads x 16 q-tiles of 64 rows
    dim3 block(256);
    attend_mfma<<<grid, block, 0, stream>>>(q, k, v, bias, out);
}

// Round 4
// 378.929 us; speedup vs baseline: 1.0795x; 1.0346x over previous
//
#include <hip/hip_runtime.h>

// Attend: out = softmax(causal(Q K^T * 0.125 + bias)) @ V
// B=4,H=16,N=1024,D=64. fp32 I/O, bf16 MFMA compute.
// Round 4: 128 q-rows/block (8 waves x 16 rows, 512 thr), K/V LDS
// double-buffered, ONE barrier per j-tile (was 2), bias double-buffered
// in regs (2-iter latency cover), per-wave masked-tile skip.
// Block-iters/CU 34->18, barriers/CU 68->18, K/V traffic halved.
// Co-resident pair {c,c+256} has strips (qs,7-qs) -> 18 iters/CU exact.

#define BHn 64
#define Nn 1024
#define Dn 64
#define NEG_BIG (-1e30f)
#define STR 72   // LDS row stride in shorts (144 B)

typedef __attribute__((ext_vector_type(8))) short short8;
typedef __attribute__((ext_vector_type(4))) float floatx4;
typedef __attribute__((ext_vector_type(4))) unsigned uint4v;

// Barrier without vmcnt(0) drain: own-LDS drain only; global prefetches
// stay in flight (counted vmcnt inserted by compiler at first use).
#define BARRIER_LDS()                                            \
    do {                                                         \
        asm volatile("s_waitcnt lgkmcnt(0)" ::: "memory");       \
        __builtin_amdgcn_s_barrier();                            \
    } while (0)

__device__ __forceinline__ unsigned cvt_pk_bf16(float lo, float hi) {
    unsigned r;
    asm("v_cvt_pk_bf16_f32 %0, %1, %2" : "=v"(r) : "v"(lo), "v"(hi));
    return r;   // packed {bf16(lo), bf16(hi)}, RNE
}

// ---- prefetch tile JT's K/V slice into regs (global, coalesced) ----
#define PREFETCH_KV(JT)                                                      \
    do {                                                                     \
        const float* kbn = kk + ((long)(bh * Nn + (JT) * 64)) * Dn + tid * 8;\
        kpf[0] = *(const floatx4*)(kbn);                                     \
        kpf[1] = *(const floatx4*)(kbn + 4);                                 \
        const float* vbn = v + ((long)(bh * Nn + (JT) * 64 + wave * 8)) * Dn \
                             + lane;                                         \
        _Pragma("unroll")                                                    \
        for (int r = 0; r < 8; ++r) vpf[r] = vbn[r * Dn];                    \
    } while (0)

// ---- stage regs -> LDS buffer BUF (cvt + one b128 write each) ----
#define STAGE_KV(BUF)                                                        \
    do {                                                                     \
        uint4v kw;                                                           \
        kw.x = cvt_pk_bf16(kpf[0][0], kpf[0][1]);                            \
        kw.y = cvt_pk_bf16(kpf[0][2], kpf[0][3]);                            \
        kw.z = cvt_pk_bf16(kpf[1][0], kpf[1][1]);                            \
        kw.w = cvt_pk_bf16(kpf[1][2], kpf[1][3]);                            \
        *(uint4v*)&k_s[BUF][krow][kcol] = kw;                                \
        uint4v vw;                                                           \
        vw.x = cvt_pk_bf16(vpf[0], vpf[1]);                                  \
        vw.y = cvt_pk_bf16(vpf[2], vpf[3]);                                  \
        vw.z = cvt_pk_bf16(vpf[4], vpf[5]);                                  \
        vw.w = cvt_pk_bf16(vpf[6], vpf[7]);                                  \
        *(uint4v*)&vt_s[BUF][lane][wave * 8] = vw;                           \
    } while (0)

// ---- bias loads for tile JT (skipped for wave-masked / OOB tiles) ----
#define LOAD_BIAS(BV, JT)                                                    \
    do {                                                                     \
        if ((JT) <= diag_jt) {                                               \
            const float* bp = bias + bias_base                               \
                              + (long)(irow0 + lg * 4) * Nn + (JT) * 64 + ln;\
            _Pragma("unroll")                                                \
            for (int r = 0; r < 4; ++r)                                      \
                _Pragma("unroll")                                            \
                for (int c = 0; c < 4; ++c)                                  \
                    BV[c][r] = bp[r * Nn + c * 16];                          \
        }                                                                    \
    } while (0)

// ---- full compute of tile JT from buffer BUF with bias BV; BIASPF is
//      issued between exp (BV dead) and PV (covers its latency) ----
#define COMPUTE(BUF, BV, JT, BIASPF)                                         \
    do {                                                                     \
        if ((JT) <= diag_jt) {                                               \
            floatx4 sfr[4];                                                  \
            __builtin_amdgcn_s_setprio(1);                                   \
            _Pragma("unroll")                                                \
            for (int nt_ = 0; nt_ < 4; ++nt_) {                              \
                short8 b0 = *(const short8*)&k_s[BUF][nt_ * 16 + ln][lg * 8];\
                short8 b1 = *(const short8*)&k_s[BUF][nt_ * 16 + ln][32 + lg * 8];\
                floatx4 acc = {0.f, 0.f, 0.f, 0.f};                          \
                acc = __builtin_amdgcn_mfma_f32_16x16x32_bf16(qa[0], b0, acc, 0, 0, 0);\
                acc = __builtin_amdgcn_mfma_f32_16x16x32_bf16(qa[1], b1, acc, 0, 0, 0);\
                sfr[nt_] = acc;                                              \
            }                                                                \
            __builtin_amdgcn_s_setprio(0);                                   \
            const bool diag = ((JT) == diag_jt);                             \
            _Pragma("unroll")                                                \
            for (int nt_ = 0; nt_ < 4; ++nt_) {                              \
                _Pragma("unroll")                                            \
                for (int r = 0; r < 4; ++r) {                                \
                    float sv = sfr[nt_][r] * 0.125f + BV[nt_][r];            \
                    if (diag) {                                              \
                        const int i_ = irow0 + lg * 4 + r;                   \
                        const int j_ = (JT) * 64 + nt_ * 16 + ln;            \
                        sv = (j_ > i_) ? NEG_BIG : sv;                       \
                    }                                                        \
                    const float p  = __expf(sv);                             \
                    const float po = __shfl_xor(p, 1);                       \
                    if (!(lane & 1))                                         \
                        *(unsigned*)&p_s[wave][lg * 4 + r][nt_ * 16 + ln] =  \
                            cvt_pk_bf16(p, po);                              \
                }                                                            \
            }                                                                \
            BIASPF;                                                          \
            const short8 pa0 = *(const short8*)&p_s[wave][ln][lg * 8];       \
            const short8 pa1 = *(const short8*)&p_s[wave][ln][32 + lg * 8];  \
            __builtin_amdgcn_s_setprio(1);                                   \
            l_acc = __builtin_amdgcn_mfma_f32_16x16x32_bf16(pa0, ones, l_acc, 0, 0, 0);\
            l_acc = __builtin_amdgcn_mfma_f32_16x16x32_bf16(pa1, ones, l_acc, 0, 0, 0);\
            _Pragma("unroll")                                                \
            for (int dt = 0; dt < 4; ++dt) {                                 \
                short8 vb0 = *(const short8*)&vt_s[BUF][dt * 16 + ln][lg * 8];\
                short8 vb1 = *(const short8*)&vt_s[BUF][dt * 16 + ln][32 + lg * 8];\
                o_acc[dt] = __builtin_amdgcn_mfma_f32_16x16x32_bf16(pa0, vb0, o_acc[dt], 0, 0, 0);\
                o_acc[dt] = __builtin_amdgcn_mfma_f32_16x16x32_bf16(pa1, vb1, o_acc[dt], 0, 0, 0);\
            }                                                                \
            __builtin_amdgcn_s_setprio(0);                                   \
        } else { BIASPF; }                                                   \
    } while (0)

__global__ __launch_bounds__(512, 4) void attend_mfma(
    const float* __restrict__ q, const float* __restrict__ kk,
    const float* __restrict__ v, const float* __restrict__ bias,
    float* __restrict__ out)
{
    // ---- balanced (head, q-strip) decode: pair {c,c+256} -> (qs, 7-qs) ----
    const int b  = blockIdx.x;
    const int bh = b & 63;                   // 8 blocks/head, head -> XCD
    const int t  = b >> 6;                   // 0..7
    const int x  = (t + bh) & 3;
    const int qs = (t < 4) ? x : (7 - x);    // q-strip (128 rows), bijective
    const int nt = 2 * qs + 2;               // j-tiles for this block (even)

    const int tid  = threadIdx.x;
    const int lane = tid & 63;
    const int wave = tid >> 6;               // 0..7
    const int ln = lane & 15;                // MFMA n / m index
    const int lg = lane >> 4;                // MFMA k-group / row-group
    const int irow0   = qs * 128 + wave * 16;
    const int diag_jt = irow0 >> 6;          // wave's last active j-tile
    const long bias_base = ((long)bh) << 20; // bh * N * N
    const int krow = tid >> 3, kcol = (tid & 7) * 8;

    __shared__ short k_s[2][64][STR];        // K tiles, row-major [j][d]
    __shared__ short vt_s[2][64][STR];       // V tiles, transposed [d][j]
    __shared__ short p_s[8][16][STR];        // per-wave P tile [m][j]

    // ---- preload Q A-frags (rows irow0..irow0+15), fp32 -> bf16 ----
    short8 qa[2];
    {
        const float* qp = q + ((long)(bh * Nn + irow0 + ln)) * Dn + lg * 8;
#pragma unroll
        for (int kp = 0; kp < 2; ++kp) {
            floatx4 f0 = *(const floatx4*)(qp + kp * 32);
            floatx4 f1 = *(const floatx4*)(qp + kp * 32 + 4);
            union { short8 s; unsigned u[4]; } qq;
            qq.u[0] = cvt_pk_bf16(f0[0], f0[1]);
            qq.u[1] = cvt_pk_bf16(f0[2], f0[3]);
            qq.u[2] = cvt_pk_bf16(f1[0], f1[1]);
            qq.u[3] = cvt_pk_bf16(f1[2], f1[3]);
            qa[kp] = qq.s;
        }
    }

    short8 ones;
#pragma unroll
    for (int i = 0; i < 8; ++i) ones[i] = (short)0x3F80;   // bf16 1.0

    floatx4 o_acc[4];
#pragma unroll
    for (int dt = 0; dt < 4; ++dt) o_acc[dt] = (floatx4){0.f, 0.f, 0.f, 0.f};
    floatx4 l_acc = {0.f, 0.f, 0.f, 0.f};

    // ---- register prefetch buffers ----
    floatx4 kpf[2];      // 8 floats: K slice (this thread)
    float   vpf[8];      // 8 floats: V slice (col=lane, 8 rows)
    float   bvA[4][4], bvB[4][4];   // bias double-buffer (even/odd tiles)

    // ---- prologue: tile 0 staged, tile 1 prefetched ----
    PREFETCH_KV(0);
    LOAD_BIAS(bvA, 0);
    STAGE_KV(0);
    if (nt > 1) { PREFETCH_KV(1); LOAD_BIAS(bvB, 1); }
    BARRIER_LDS();

    // ---- main loop: unrolled by 2 (nt is always even) ----
    for (int jt = 0; jt < nt; jt += 2) {
        // even tile jt (buf 0): stage jt+1, prefetch jt+2
        STAGE_KV(1);                                  // tile jt+1 -> buf1
        if (jt + 2 < nt) PREFETCH_KV(jt + 2);
        COMPUTE(0, bvA, jt, LOAD_BIAS(bvA, jt + 2));
        BARRIER_LDS();

        // odd tile jt+1 (buf 1): stage jt+2, prefetch jt+3
        if (jt + 2 < nt) STAGE_KV(0);                 // tile jt+2 -> buf0
        if (jt + 3 < nt) PREFETCH_KV(jt + 3);
        COMPUTE(1, bvB, jt + 1, LOAD_BIAS(bvB, jt + 3));
        BARRIER_LDS();
    }

    // ---- epilogue: out = O / l, fp32 stores ----
#pragma unroll
    for (int r = 0; r < 4; ++r) {
        const float linv = 1.0f / l_acc[r];
        const long orow = ((long)(bh * Nn + irow0 + lg * 4 + r)) * Dn;
#pragma unroll
        for (int dt = 0; dt < 4; ++dt)
            out[orow + dt * 16 + ln] = o_acc[dt][r] * linv;
    }
}

extern "C" void kernel_launch(void* const* d_in, const int* in_sizes, int n_in,
                              void* d_out, int out_size, void* d_ws, size_t ws_size,
                              hipStream_t stream) {
    const float* q    = (const float*)d_in[0];
    const float* k    = (const float*)d_in[1];
    const float* v    = (const float*)d_in[2];
    const float* bias = (const float*)d_in[3];
    float* out = (float*)d_out;

    dim3 grid(512);    // 64 heads x 8 q-strips of 128 rows
    dim3 block(512);   // 8 waves x 16 rows
    attend_mfma<<<grid, block, 0, stream>>>(q, k, v, bias, out);
}